// Round 1
// baseline (85.095 us; speedup 1.0000x reference)
//
#include <hip/hip_runtime.h>
#include <hip/hip_bf16.h>
#include <math.h>

#define N_NEUR 2048
#define EMB 1024
#define S_TOT 8192
#define WMAX 2048
#define NW 12

typedef __attribute__((ext_vector_type(8))) short bf16x8;
typedef __attribute__((ext_vector_type(4))) float f32x4;
typedef __attribute__((ext_vector_type(4))) int int4v;

__device__ inline short f2bf(float f) {
    union { float f; unsigned u; } v; v.f = f;
    unsigned r = v.u + 0x7FFFu + ((v.u >> 16) & 1u);   // RNE
    return (short)(r >> 16);
}

// Cast x-tail (rows 6144..8191) and n_weights to bf16.
__global__ __launch_bounds__(256) void precast(const float* __restrict__ xt,
                                               const float* __restrict__ nw,
                                               short* __restrict__ A,
                                               short* __restrict__ W) {
    const int HALF = (N_NEUR * EMB) / 4;   // 524288 float4 groups per matrix
    int g = blockIdx.x * 256 + threadIdx.x;
    const float4* src; short* dst;
    if (g < HALF) { src = (const float4*)xt; dst = A; }
    else          { g -= HALF; src = (const float4*)nw; dst = W; }
    float4 v = src[g];
    short4 o;
    o.x = f2bf(v.x); o.y = f2bf(v.y); o.z = f2bf(v.z); o.w = f2bf(v.w);
    *(short4*)(dst + (size_t)g * 4) = o;
}

// act[i][n] = tanh( sum_e A[i][e] * W[n][e] + bias[n] ), 2048x2048, K=1024.
// 128x128 tile / block (4 waves, 2x2 of 64x64), 16x16x32 bf16 MFMA, B^T layout.
#define BK 32
#define LDK 40   // padded LDS row stride (80 B, 16B-aligned, conflict-free b128)

__global__ __launch_bounds__(256) void gemm_act(const short* __restrict__ A,
                                                const short* __restrict__ W,
                                                const float* __restrict__ bias,
                                                float* __restrict__ act) {
    __shared__ short As[128 * LDK];
    __shared__ short Bs[128 * LDK];
    const int t = threadIdx.x;
    const int bm = blockIdx.y, bn = blockIdx.x;
    const int lane = t & 63, wid = t >> 6;
    const int wr = wid >> 1, wc = wid & 1;
    const int l15 = lane & 15, lhi = lane >> 4;
    const int srow = t >> 1, scol = (t & 1) * 16;   // 2 threads/row, 16 shorts each
    const short* gA = A + (size_t)(bm * 128 + srow) * EMB + scol;
    const short* gW = W + (size_t)(bn * 128 + srow) * EMB + scol;
    short* wA = &As[srow * LDK + scol];
    short* wB = &Bs[srow * LDK + scol];
    f32x4 acc[4][4] = {};
    for (int k0 = 0; k0 < EMB; k0 += BK) {
        __syncthreads();
        int4v a0 = *(const int4v*)(gA + k0);
        int4v a1 = *(const int4v*)(gA + k0 + 8);
        int4v b0 = *(const int4v*)(gW + k0);
        int4v b1 = *(const int4v*)(gW + k0 + 8);
        *(int4v*)wA = a0; *(int4v*)(wA + 8) = a1;
        *(int4v*)wB = b0; *(int4v*)(wB + 8) = b1;
        __syncthreads();
        bf16x8 af[4], bb[4];
        #pragma unroll
        for (int m = 0; m < 4; ++m)
            af[m] = *(const bf16x8*)&As[(wr * 64 + m * 16 + l15) * LDK + lhi * 8];
        #pragma unroll
        for (int n = 0; n < 4; ++n)
            bb[n] = *(const bf16x8*)&Bs[(wc * 64 + n * 16 + l15) * LDK + lhi * 8];
        #pragma unroll
        for (int m = 0; m < 4; ++m)
            #pragma unroll
            for (int n = 0; n < 4; ++n)
                acc[m][n] = __builtin_amdgcn_mfma_f32_16x16x32_bf16(af[m], bb[n], acc[m][n], 0, 0, 0);
    }
    // epilogue: C/D layout col=lane&15, row=(lane>>4)*4+j  (m89-verified)
    #pragma unroll
    for (int n = 0; n < 4; ++n) {
        int col = bn * 128 + wc * 64 + n * 16 + l15;
        float bc = bias[col];
        #pragma unroll
        for (int m = 0; m < 4; ++m) {
            int rbase = bm * 128 + wr * 64 + m * 16 + lhi * 4;
            #pragma unroll
            for (int j = 0; j < 4; ++j)
                act[(size_t)(rbase + j) * N_NEUR + col] = tanhf(acc[m][n][j] + bc);
        }
    }
}

// Segment sums over disjoint row ranges [0,1),[1,2),[2,4),...,[1024,2048).
__global__ __launch_bounds__(256) void segsum(const float* __restrict__ act,
                                              float* __restrict__ seg) {
    int c = blockIdx.x * 256 + threadIdx.x;   // column (neuron)
    int rc = blockIdx.y;                      // 32-row chunk
    if (rc == 0) {
        float s = 0.f; int cur = 0;
        for (int i = 0; i < 32; ++i) {
            int sj = (i == 0) ? 0 : (32 - __clz(i));
            if (sj != cur) { atomicAdd(&seg[cur * N_NEUR + c], s); s = 0.f; cur = sj; }
            s += act[(size_t)i * N_NEUR + c];
        }
        atomicAdd(&seg[cur * N_NEUR + c], s);
    } else {
        int r0 = rc * 32;
        float s = 0.f;
        #pragma unroll 8
        for (int i = 0; i < 32; ++i) s += act[(size_t)(r0 + i) * N_NEUR + c];
        int j = 37 - __clz(rc);               // chunk lies wholly in one segment
        atomicAdd(&seg[j * N_NEUR + c], s);
    }
}

// window_out[w][n] = (prefix sum of segments) / 2^w
__global__ __launch_bounds__(256) void winout(const float* __restrict__ seg,
                                              float* __restrict__ wout) {
    int n = blockIdx.x * 256 + threadIdx.x;
    float run = 0.f;
    #pragma unroll
    for (int w = 0; w < NW; ++w) {
        run += seg[w * N_NEUR + n];
        wout[w * N_NEUR + n] = run * (1.0f / (float)(1 << w));
    }
}

// acc[m] += dot(combo_w[w][m][:], window_out[w][:]) ; one wave per (w,m) row.
__global__ __launch_bounds__(256) void combo_dot(const float* __restrict__ cw,
                                                 const float* __restrict__ wout,
                                                 float* __restrict__ acc) {
    int wid = threadIdx.x >> 6, lane = threadIdx.x & 63;
    int r = blockIdx.x * 4 + wid;             // 0..24575
    int w = r >> 11, m = r & 2047;
    const float4* row  = (const float4*)(cw + (size_t)(w * N_NEUR + m) * N_NEUR);
    const float4* wrow = (const float4*)(wout + w * N_NEUR);
    float s = 0.f;
    #pragma unroll
    for (int i = 0; i < 8; ++i) {
        float4 a = row[i * 64 + lane];
        float4 b = wrow[i * 64 + lane];
        s += a.x * b.x + a.y * b.y + a.z * b.z + a.w * b.w;
    }
    #pragma unroll
    for (int off = 32; off > 0; off >>= 1) s += __shfl_down(s, off);
    if (lane == 0) atomicAdd(&acc[m], s);
}

// out[m] = (61/60) * (acc[m] + sum_w combo_b[w][m]) + 1.0   (softmax sums to 1)
__global__ __launch_bounds__(256) void finalize(const float* __restrict__ acc,
                                                const float* __restrict__ cb,
                                                float* __restrict__ out) {
    int m = blockIdx.x * 256 + threadIdx.x;
    float bs = 0.f;
    #pragma unroll
    for (int w = 0; w < NW; ++w) bs += cb[w * N_NEUR + m];
    out[m] = 1.0166666666666666f * (acc[m] + bs) + 1.0f;
}

extern "C" void kernel_launch(void* const* d_in, const int* in_sizes, int n_in,
                              void* d_out, int out_size, void* d_ws, size_t ws_size,
                              hipStream_t stream) {
    const float* x  = (const float*)d_in[0];
    const float* nw = (const float*)d_in[1];
    const float* nb = (const float*)d_in[2];
    const float* cw = (const float*)d_in[3];
    const float* cb = (const float*)d_in[4];
    float* out = (float*)d_out;

    char* ws = (char*)d_ws;
    float* acc  = (float*)ws;                              // 2048 f32      (8 KB)
    float* seg  = (float*)(ws + 8192);                     // 12*2048 f32   (96 KB)
    float* wout = (float*)(ws + 8192 + 98304);             // 12*2048 f32   (96 KB)
    short* Abf  = (short*)(ws + 204800);                   // 2048*1024 bf16 (4 MB)
    short* Wbf  = (short*)(ws + 204800 + 4194304);         // 2048*1024 bf16 (4 MB)
    float* act  = (float*)(ws + 204800 + 8388608);         // 2048*2048 f32 (16 MB)

    hipMemsetAsync(ws, 0, 106496, stream);                 // zero acc + seg

    precast<<<4096, 256, 0, stream>>>(x + (size_t)(S_TOT - WMAX) * EMB, nw, Abf, Wbf);

    dim3 g1(16, 16);
    gemm_act<<<g1, 256, 0, stream>>>(Abf, Wbf, nb, act);

    dim3 g2(8, 64);
    segsum<<<g2, 256, 0, stream>>>(act, seg);

    winout<<<8, 256, 0, stream>>>(seg, wout);

    combo_dot<<<6144, 256, 0, stream>>>(cw, wout, acc);

    finalize<<<8, 256, 0, stream>>>(acc, cb, out);
}

// Round 3
// 68.242 us; speedup vs baseline: 1.2470x; 1.2470x over previous
//
#include <hip/hip_runtime.h>
#include <hip/hip_bf16.h>
#include <math.h>

#define N_NEUR 2048
#define EMB 1024
#define S_TOT 8192
#define WMAX 2048
#define NW 12

typedef __attribute__((ext_vector_type(8))) short bf16x8;
typedef __attribute__((ext_vector_type(4))) float f32x4;
typedef __attribute__((ext_vector_type(4))) int int4v;

__device__ inline short f2bf(float f) {
    union { float f; unsigned u; } v; v.f = f;
    unsigned r = v.u + 0x7FFFu + ((v.u >> 16) & 1u);   // RNE
    return (short)(r >> 16);
}

// Cast x-tail (rows 6144..8191) and n_weights to bf16.
__global__ __launch_bounds__(256) void precast(const float* __restrict__ xt,
                                               const float* __restrict__ nw,
                                               short* __restrict__ A,
                                               short* __restrict__ W) {
    const int HALF = (N_NEUR * EMB) / 4;   // 524288 float4 groups per matrix
    int g = blockIdx.x * 256 + threadIdx.x;
    const float4* src; short* dst;
    if (g < HALF) { src = (const float4*)xt; dst = A; }
    else          { g -= HALF; src = (const float4*)nw; dst = W; }
    float4 v = src[g];
    short4 o;
    o.x = f2bf(v.x); o.y = f2bf(v.y); o.z = f2bf(v.z); o.w = f2bf(v.w);
    *(short4*)(dst + (size_t)g * 4) = o;
}

// Fused GEMM + tanh + segment-sum.  64x64 tile, BK=64, 4 waves (2x2 of 32x32).
// seg[j][n] = sum over rows i in [2^(j-1), 2^j) of tanh(gemm[i][n] + bias[n]).
// act matrix is never materialized.
#define LDK 72   // padded LDS row stride in shorts (144 B, 16B-aligned)

__global__ __launch_bounds__(256) void gemm_seg(const short* __restrict__ A,
                                                const short* __restrict__ W,
                                                const float* __restrict__ bias,
                                                float* __restrict__ seg) {
    __shared__ short As[64 * LDK];
    __shared__ short Bs[64 * LDK];
    const int t = threadIdx.x;
    const int bm = blockIdx.y, bn = blockIdx.x;
    const int lane = t & 63, wid = t >> 6;
    const int wr = wid >> 1, wc = wid & 1;
    const int l15 = lane & 15, lhi = lane >> 4;
    const int srow = t >> 2, scol = (t & 3) * 16;   // 4 threads/row, 16 shorts each
    const short* gA = A + (size_t)(bm * 64 + srow) * EMB + scol;
    const short* gW = W + (size_t)(bn * 64 + srow) * EMB + scol;
    short* wA = &As[srow * LDK + scol];
    short* wB = &Bs[srow * LDK + scol];
    f32x4 acc[2][2] = {};
    for (int k0 = 0; k0 < EMB; k0 += 64) {
        __syncthreads();
        int4v a0 = *(const int4v*)(gA + k0);
        int4v a1 = *(const int4v*)(gA + k0 + 8);
        int4v b0 = *(const int4v*)(gW + k0);
        int4v b1 = *(const int4v*)(gW + k0 + 8);
        *(int4v*)wA = a0; *(int4v*)(wA + 8) = a1;
        *(int4v*)wB = b0; *(int4v*)(wB + 8) = b1;
        __syncthreads();
        bf16x8 af[2][2], bb[2][2];
        #pragma unroll
        for (int kk = 0; kk < 2; ++kk) {
            #pragma unroll
            for (int m = 0; m < 2; ++m)
                af[kk][m] = *(const bf16x8*)&As[(wr * 32 + m * 16 + l15) * LDK + kk * 32 + lhi * 8];
            #pragma unroll
            for (int n = 0; n < 2; ++n)
                bb[kk][n] = *(const bf16x8*)&Bs[(wc * 32 + n * 16 + l15) * LDK + kk * 32 + lhi * 8];
        }
        #pragma unroll
        for (int kk = 0; kk < 2; ++kk)
            #pragma unroll
            for (int m = 0; m < 2; ++m)
                #pragma unroll
                for (int n = 0; n < 2; ++n)
                    acc[m][n] = __builtin_amdgcn_mfma_f32_16x16x32_bf16(af[kk][m], bb[kk][n], acc[m][n], 0, 0, 0);
    }
    // Epilogue. C/D layout: col = lane&15, row(within frag) = lhi*4 + j.
    // Block rows [bm*64, bm*64+64).  For bm>=1 the whole block is inside one
    // segment (power-of-2 boundaries >=64 are multiples of 64).
    if (bm > 0) {
        int jseg = 38 - __clz(bm);   // floor(log2(bm*64)) + 1
        #pragma unroll
        for (int n = 0; n < 2; ++n) {
            int col = bn * 64 + wc * 32 + n * 16 + l15;
            float bc = bias[col];
            float s = 0.f;
            #pragma unroll
            for (int m = 0; m < 2; ++m)
                #pragma unroll
                for (int j = 0; j < 4; ++j)
                    s += tanhf(acc[m][n][j] + bc);
            s += __shfl_xor(s, 16);
            s += __shfl_xor(s, 32);
            if (lhi == 0) atomicAdd(&seg[jseg * N_NEUR + col], s);
        }
    } else {
        // rows 0..63: wr=1 -> rows 32..63 (seg 6); wr=0,m=1 -> rows 16..31 (seg 5);
        // wr=0,m=0 -> rows 0..15 (per-row segments 0..4).
        #pragma unroll
        for (int n = 0; n < 2; ++n) {
            int col = bn * 64 + wc * 32 + n * 16 + l15;
            float bc = bias[col];
            if (wr == 1) {
                float s = 0.f;
                #pragma unroll
                for (int m = 0; m < 2; ++m)
                    #pragma unroll
                    for (int j = 0; j < 4; ++j)
                        s += tanhf(acc[m][n][j] + bc);
                s += __shfl_xor(s, 16);
                s += __shfl_xor(s, 32);
                if (lhi == 0) atomicAdd(&seg[6 * N_NEUR + col], s);
            } else {
                // m=1: rows 16..31, segment 5
                float s = 0.f;
                #pragma unroll
                for (int j = 0; j < 4; ++j)
                    s += tanhf(acc[1][n][j] + bc);
                s += __shfl_xor(s, 16);
                s += __shfl_xor(s, 32);
                if (lhi == 0) atomicAdd(&seg[5 * N_NEUR + col], s);
                // m=0: rows 0..15, per-row segment
                #pragma unroll
                for (int j = 0; j < 4; ++j) {
                    int r = lhi * 4 + j;
                    int sj = (r == 0) ? 0 : (32 - __clz(r));
                    atomicAdd(&seg[sj * N_NEUR + col], tanhf(acc[0][n][j] + bc));
                }
            }
        }
    }
}

// window_out[w][n] = (prefix sum of segments) / 2^w
__global__ __launch_bounds__(256) void winout(const float* __restrict__ seg,
                                              float* __restrict__ wout) {
    int n = blockIdx.x * 256 + threadIdx.x;
    float run = 0.f;
    #pragma unroll
    for (int w = 0; w < NW; ++w) {
        run += seg[w * N_NEUR + n];
        wout[w * N_NEUR + n] = run * (1.0f / (float)(1 << w));
    }
}

// acc[m] += dot(combo_w[w][m][:], window_out[w][:]) ; one wave per (w,m) row.
__global__ __launch_bounds__(256) void combo_dot(const float* __restrict__ cw,
                                                 const float* __restrict__ wout,
                                                 float* __restrict__ acc) {
    int wid = threadIdx.x >> 6, lane = threadIdx.x & 63;
    int r = blockIdx.x * 4 + wid;             // 0..24575
    int w = r >> 11, m = r & 2047;
    const float4* row  = (const float4*)(cw + (size_t)(w * N_NEUR + m) * N_NEUR);
    const float4* wrow = (const float4*)(wout + w * N_NEUR);
    float s = 0.f;
    #pragma unroll
    for (int i = 0; i < 8; ++i) {
        float4 a = row[i * 64 + lane];
        float4 b = wrow[i * 64 + lane];
        s += a.x * b.x + a.y * b.y + a.z * b.z + a.w * b.w;
    }
    #pragma unroll
    for (int off = 32; off > 0; off >>= 1) s += __shfl_down(s, off);
    if (lane == 0) atomicAdd(&acc[m], s);
}

// out[m] = (61/60) * (acc[m] + sum_w combo_b[w][m]) + 1.0   (softmax sums to 1)
__global__ __launch_bounds__(256) void finalize(const float* __restrict__ acc,
                                                const float* __restrict__ cb,
                                                float* __restrict__ out) {
    int m = blockIdx.x * 256 + threadIdx.x;
    float bs = 0.f;
    #pragma unroll
    for (int w = 0; w < NW; ++w) bs += cb[w * N_NEUR + m];
    out[m] = 1.0166666666666666f * (acc[m] + bs) + 1.0f;
}

extern "C" void kernel_launch(void* const* d_in, const int* in_sizes, int n_in,
                              void* d_out, int out_size, void* d_ws, size_t ws_size,
                              hipStream_t stream) {
    const float* x  = (const float*)d_in[0];
    const float* nw = (const float*)d_in[1];
    const float* nb = (const float*)d_in[2];
    const float* cw = (const float*)d_in[3];
    const float* cb = (const float*)d_in[4];
    float* out = (float*)d_out;

    char* ws = (char*)d_ws;
    float* acc  = (float*)ws;                              // 2048 f32      (8 KB)
    float* seg  = (float*)(ws + 8192);                     // 12*2048 f32   (96 KB)
    float* wout = (float*)(ws + 8192 + 98304);             // 12*2048 f32   (96 KB)
    short* Abf  = (short*)(ws + 204800);                   // 2048*1024 bf16 (4 MB)
    short* Wbf  = (short*)(ws + 204800 + 4194304);         // 2048*1024 bf16 (4 MB)

    hipMemsetAsync(ws, 0, 106496, stream);                 // zero acc + seg

    precast<<<4096, 256, 0, stream>>>(x + (size_t)(S_TOT - WMAX) * EMB, nw, Abf, Wbf);

    dim3 g1(32, 32);
    gemm_seg<<<g1, 256, 0, stream>>>(Abf, Wbf, nb, seg);

    winout<<<8, 256, 0, stream>>>(seg, wout);

    combo_dot<<<6144, 256, 0, stream>>>(cw, wout, acc);

    finalize<<<8, 256, 0, stream>>>(acc, cb, out);
}

// Round 4
// 61.673 us; speedup vs baseline: 1.3798x; 1.1065x over previous
//
#include <hip/hip_runtime.h>
#include <hip/hip_bf16.h>
#include <math.h>

#define N_NEUR 2048
#define EMB 1024
#define S_TOT 8192
#define WMAX 2048
#define NW 12

typedef __attribute__((ext_vector_type(8))) short bf16x8;
typedef __attribute__((ext_vector_type(4))) float f32x4;

__device__ inline short f2bf(float f) {
    union { float f; unsigned u; } v; v.f = f;
    unsigned r = v.u + 0x7FFFu + ((v.u >> 16) & 1u);   // RNE
    return (short)(r >> 16);
}

// Cast x-tail (rows 6144..8191) and n_weights to bf16 (row-major, unpermuted).
__global__ __launch_bounds__(256) void precast(const float* __restrict__ xt,
                                               const float* __restrict__ nw,
                                               short* __restrict__ A,
                                               short* __restrict__ W) {
    const int HALF = (N_NEUR * EMB) / 4;   // 524288 float4 groups per matrix
    int g = blockIdx.x * 256 + threadIdx.x;
    const float4* src; short* dst;
    if (g < HALF) { src = (const float4*)xt; dst = A; }
    else          { g -= HALF; src = (const float4*)nw; dst = W; }
    float4 v = src[g];
    short4 o;
    o.x = f2bf(v.x); o.y = f2bf(v.y); o.z = f2bf(v.z); o.w = f2bf(v.w);
    *(short4*)(dst + (size_t)g * 4) = o;
}

// Fused GEMM + tanh + segment-sum.  64x64 tile, BK=64, 4 waves (2x2 of 32x32).
// global_load_lds(16B) staging, double-buffered LDS, one barrier per K-step.
// LDS layout is linear [64][64] shorts; XOR slot-swizzle (slot ^= row&7 at
// 16B granularity) applied on BOTH the per-lane global source address and the
// ds_read address (rule 21: both-sides-or-neither).
#define GLDS(g, l) __builtin_amdgcn_global_load_lds(                          \
    (const __attribute__((address_space(1))) void*)(g),                       \
    (__attribute__((address_space(3))) void*)(l), 16, 0, 0)

__global__ __launch_bounds__(256) void gemm_seg(const short* __restrict__ A,
                                                const short* __restrict__ W,
                                                const float* __restrict__ bias,
                                                float* __restrict__ seg) {
    __shared__ short As[2][64 * 64];
    __shared__ short Bs[2][64 * 64];
    const int t = threadIdx.x;
    const int bm = blockIdx.y, bn = blockIdx.x;
    const int lane = t & 63, wid = t >> 6;
    const int wr = wid >> 1, wc = wid & 1;
    const int l15 = lane & 15, lhi = lane >> 4;
    // Staging: wave wid stages rows [wid*16, wid*16+16) of each tile in two
    // 8-row 1KB issues.  lane -> (row = base + (lane>>3), slot = lane&7);
    // global source slot pre-permuted: pslot = slot ^ (row&7) = (lane&7)^(lane>>3).
    const int srow = lane >> 3;            // 0..7 within issue
    const int pslot = (lane & 7) ^ srow;   // pre-swizzled source slot
    const short* gA0 = A + (size_t)(bm * 64 + wid * 16 + 0 + srow) * EMB + pslot * 8;
    const short* gA1 = A + (size_t)(bm * 64 + wid * 16 + 8 + srow) * EMB + pslot * 8;
    const short* gB0 = W + (size_t)(bn * 64 + wid * 16 + 0 + srow) * EMB + pslot * 8;
    const short* gB1 = W + (size_t)(bn * 64 + wid * 16 + 8 + srow) * EMB + pslot * 8;
    short* lA0[2] = { &As[0][(wid * 16 + 0) * 64], &As[1][(wid * 16 + 0) * 64] };
    short* lA1[2] = { &As[0][(wid * 16 + 8) * 64], &As[1][(wid * 16 + 8) * 64] };
    short* lB0[2] = { &Bs[0][(wid * 16 + 0) * 64], &Bs[1][(wid * 16 + 0) * 64] };
    short* lB1[2] = { &Bs[0][(wid * 16 + 8) * 64], &Bs[1][(wid * 16 + 8) * 64] };

    f32x4 acc[2][2] = {};

    // prologue: stage tile 0 into buffer 0
    GLDS(gA0, lA0[0]); GLDS(gA1, lA1[0]);
    GLDS(gB0, lB0[0]); GLDS(gB1, lB1[0]);
    __syncthreads();                       // drains vmcnt -> buf0 ready

    int cur = 0;
    for (int ks = 0; ks < 16; ++ks) {
        if (ks < 15) {                     // prefetch next tile into buf^1
            int k0 = (ks + 1) * 64;
            GLDS(gA0 + k0, lA0[cur ^ 1]); GLDS(gA1 + k0, lA1[cur ^ 1]);
            GLDS(gB0 + k0, lB0[cur ^ 1]); GLDS(gB1 + k0, lB1[cur ^ 1]);
        }
        bf16x8 af[2][2], bb[2][2];
        #pragma unroll
        for (int kk = 0; kk < 2; ++kk) {
            #pragma unroll
            for (int m = 0; m < 2; ++m) {
                int row = wr * 32 + m * 16 + l15;
                int slot = (kk * 4 + lhi) ^ (row & 7);
                af[kk][m] = *(const bf16x8*)&As[cur][row * 64 + slot * 8];
            }
            #pragma unroll
            for (int n = 0; n < 2; ++n) {
                int row = wc * 32 + n * 16 + l15;
                int slot = (kk * 4 + lhi) ^ (row & 7);
                bb[kk][n] = *(const bf16x8*)&Bs[cur][row * 64 + slot * 8];
            }
        }
        __builtin_amdgcn_s_setprio(1);
        #pragma unroll
        for (int kk = 0; kk < 2; ++kk)
            #pragma unroll
            for (int m = 0; m < 2; ++m)
                #pragma unroll
                for (int n = 0; n < 2; ++n)
                    acc[m][n] = __builtin_amdgcn_mfma_f32_16x16x32_bf16(af[kk][m], bb[kk][n], acc[m][n], 0, 0, 0);
        __builtin_amdgcn_s_setprio(0);
        __syncthreads();                   // stage of buf^1 complete; reads of cur done
        cur ^= 1;
    }

    // Epilogue. C/D layout: col = lane&15, row(within frag) = lhi*4 + j.
    if (bm > 0) {
        int jseg = 38 - __clz(bm);   // floor(log2(bm*64)) + 1
        #pragma unroll
        for (int n = 0; n < 2; ++n) {
            int col = bn * 64 + wc * 32 + n * 16 + l15;
            float bc = bias[col];
            float s = 0.f;
            #pragma unroll
            for (int m = 0; m < 2; ++m)
                #pragma unroll
                for (int j = 0; j < 4; ++j)
                    s += tanhf(acc[m][n][j] + bc);
            s += __shfl_xor(s, 16);
            s += __shfl_xor(s, 32);
            if (lhi == 0) atomicAdd(&seg[jseg * N_NEUR + col], s);
        }
    } else {
        #pragma unroll
        for (int n = 0; n < 2; ++n) {
            int col = bn * 64 + wc * 32 + n * 16 + l15;
            float bc = bias[col];
            if (wr == 1) {                 // rows 32..63 -> seg 6
                float s = 0.f;
                #pragma unroll
                for (int m = 0; m < 2; ++m)
                    #pragma unroll
                    for (int j = 0; j < 4; ++j)
                        s += tanhf(acc[m][n][j] + bc);
                s += __shfl_xor(s, 16);
                s += __shfl_xor(s, 32);
                if (lhi == 0) atomicAdd(&seg[6 * N_NEUR + col], s);
            } else {
                float s = 0.f;             // rows 16..31 -> seg 5
                #pragma unroll
                for (int j = 0; j < 4; ++j)
                    s += tanhf(acc[1][n][j] + bc);
                s += __shfl_xor(s, 16);
                s += __shfl_xor(s, 32);
                if (lhi == 0) atomicAdd(&seg[5 * N_NEUR + col], s);
                #pragma unroll
                for (int j = 0; j < 4; ++j) {  // rows 0..15 per-row segments
                    int r = lhi * 4 + j;
                    int sj = (r == 0) ? 0 : (32 - __clz(r));
                    atomicAdd(&seg[sj * N_NEUR + col], tanhf(acc[0][n][j] + bc));
                }
            }
        }
    }
}

// wout[w][n] = prefix(seg)/2^w  AND  out[n] = (61/60)*sum_w cb[w][n] + 1.
__global__ __launch_bounds__(256) void winout_init(const float* __restrict__ seg,
                                                   const float* __restrict__ cb,
                                                   float* __restrict__ wout,
                                                   float* __restrict__ out) {
    int n = blockIdx.x * 256 + threadIdx.x;
    float run = 0.f;
    #pragma unroll
    for (int w = 0; w < NW; ++w) {
        run += seg[w * N_NEUR + n];
        wout[w * N_NEUR + n] = run * (1.0f / (float)(1 << w));
    }
    float bs = 0.f;
    #pragma unroll
    for (int w = 0; w < NW; ++w) bs += cb[w * N_NEUR + n];
    out[n] = 1.0166666666666666f * bs + 1.0f;
}

// out[m] += (61/60) * dot(combo_w[w][m][:], wout[w][:]) ; one wave per (w,m).
__global__ __launch_bounds__(256) void combo_dot(const float* __restrict__ cw,
                                                 const float* __restrict__ wout,
                                                 float* __restrict__ out) {
    int wid = threadIdx.x >> 6, lane = threadIdx.x & 63;
    int r = blockIdx.x * 4 + wid;             // 0..24575
    int w = r >> 11, m = r & 2047;
    const float4* row  = (const float4*)(cw + (size_t)(w * N_NEUR + m) * N_NEUR);
    const float4* wrow = (const float4*)(wout + w * N_NEUR);
    float s = 0.f;
    #pragma unroll
    for (int i = 0; i < 8; ++i) {
        float4 a = row[i * 64 + lane];
        float4 b = wrow[i * 64 + lane];
        s += a.x * b.x + a.y * b.y + a.z * b.z + a.w * b.w;
    }
    #pragma unroll
    for (int off = 32; off > 0; off >>= 1) s += __shfl_down(s, off);
    if (lane == 0) atomicAdd(&out[m], 1.0166666666666666f * s);
}

extern "C" void kernel_launch(void* const* d_in, const int* in_sizes, int n_in,
                              void* d_out, int out_size, void* d_ws, size_t ws_size,
                              hipStream_t stream) {
    const float* x  = (const float*)d_in[0];
    const float* nw = (const float*)d_in[1];
    const float* nb = (const float*)d_in[2];
    const float* cw = (const float*)d_in[3];
    const float* cb = (const float*)d_in[4];
    float* out = (float*)d_out;

    char* ws = (char*)d_ws;
    float* seg  = (float*)ws;                              // 12*2048 f32   (96 KB)
    float* wout = (float*)(ws + 98304);                    // 12*2048 f32   (96 KB)
    short* Abf  = (short*)(ws + 204800);                   // 2048*1024 bf16 (4 MB)
    short* Wbf  = (short*)(ws + 204800 + 4194304);         // 2048*1024 bf16 (4 MB)

    hipMemsetAsync(ws, 0, 98304, stream);                  // zero seg

    precast<<<4096, 256, 0, stream>>>(x + (size_t)(S_TOT - WMAX) * EMB, nw, Abf, Wbf);

    dim3 g1(32, 32);
    gemm_seg<<<g1, 256, 0, stream>>>(Abf, Wbf, nb, seg);

    winout_init<<<8, 256, 0, stream>>>(seg, cb, wout, out);

    combo_dot<<<6144, 256, 0, stream>>>(cw, wout, out);
}